// Round 5
// baseline (328.025 us; speedup 1.0000x reference)
//
#include <hip/hip_runtime.h>

// Pipeline (5 kernels):
//   k_prep_w : attn_W -> Wa bf16 (rows 200..207 zero), fc_W -> Wf bf16 (remapped, gap zero)
//   k_gemm1  : region partials = imgtag @ Wa^T, K-SPLIT 2 (grid 1152 = 4.5 blk/CU).
//              A: f32 -> bf16 fused (reg-prefetch, write-through to Abf). B: Wa via gl16.
//   k_attn   : sums partials, tanh-softmax attention, boxfeat -> Abf cols 2048..2303
//   k_gemm2  : dout = Abf @ Wf^T, 128x128, grid (8,72) n-fastest for A-panel reuse
//   k_norm   : bias + L2 normalize in place
// Workspace (79,421,440 B):
//   Abf[9216][3072] bf16 | Wf[1024][3072] bf16 | Wa[208][2816] bf16 | regP[2][9216][208] f32
//
// LESSONS: (R3) dbuf+1-barrier kills blocks/CU, __syncthreads drains vmcnt(0) anyway ->
// TLP is the lever, not intra-block pipelining. (R2) B-operand direct L2->reg puts
// scattered-load latency on the MFMA chain -> keep B in LDS via gl16.

#define M_TOT 9216
#define K1    2816
#define K2    3072
#define ES    1024
#define REGN  (9216L * 208)

typedef __attribute__((ext_vector_type(8))) short bf16x8;
typedef __attribute__((ext_vector_type(4))) float floatx4;

static __device__ __forceinline__ unsigned short f2bf(float f) {
    unsigned int u = __float_as_uint(f);
    u += 0x7fffu + ((u >> 16) & 1u);   // RNE
    return (unsigned short)(u >> 16);
}

static __device__ __forceinline__ uint4 pack8(const float4 f0, const float4 f1) {
    uint4 pk;
    pk.x = (unsigned)f2bf(f0.x) | ((unsigned)f2bf(f0.y) << 16);
    pk.y = (unsigned)f2bf(f0.z) | ((unsigned)f2bf(f0.w) << 16);
    pk.z = (unsigned)f2bf(f1.x) | ((unsigned)f2bf(f1.y) << 16);
    pk.w = (unsigned)f2bf(f1.z) | ((unsigned)f2bf(f1.w) << 16);
    return pk;
}

static __device__ __forceinline__ void cvt8(const float* __restrict__ g,
                                            unsigned short* __restrict__ d) {
    *(uint4*)d = pack8(*(const float4*)g, *(const float4*)(g + 4));
}

// async global->LDS, 16 B per lane; LDS dest must be wave-uniform base (+lane*16)
static __device__ __forceinline__ void gl16(const void* g, const void* l) {
    __builtin_amdgcn_global_load_lds(
        (const __attribute__((address_space(1))) unsigned int*)g,
        (__attribute__((address_space(3))) unsigned int*)(unsigned int)(unsigned long long)l,
        16, 0, 0);
}

// ============ prep weights only: Wa + Wf (bf16, padded/remapped) ============
#define NC_WF  (1024 * 384)
#define NC_WA  ( 208 * 352)
__global__ __launch_bounds__(256) void k_prep_w(
    const float* __restrict__ attn_W,   // [200][2816]
    const float* __restrict__ fc_W,     // [1024][3016]
    unsigned short* __restrict__ Wa,    // [208][2816]
    unsigned short* __restrict__ Wf)    // [1024][3072]
{
    const int u = blockIdx.x * 256 + threadIdx.x;
    uint4 z; z.x = z.y = z.z = z.w = 0u;
    if (u < NC_WF) {
        const int r = u / 384;
        const int dc = (u - r * 384) * 8;
        unsigned short* d = Wf + (long)r * K2 + dc;
        if (dc < 2248)      cvt8(fc_W + (long)r * 3016 + dc, d);        // img+box cols
        else if (dc < 2304) *(uint4*)d = z;                             // zero gap
        else                cvt8(fc_W + (long)r * 3016 + (dc - 56), d); // tag cols
    } else if (u < NC_WF + NC_WA) {
        const int v = u - NC_WF;
        const int r = v / 352;
        const int c = (v - r * 352) * 8;
        if (r < 200) cvt8(attn_W + (long)r * K1 + c, Wa + (long)r * K1 + c);
        else         *(uint4*)(Wa + (long)r * K1 + c) = z;
    }
}

// ============ GEMM1: region partials, K-split 2 ============
// grid 1152 x 256. Block (bid>>1 = m-tile, bid&1 = K-half): 16 rows x 208 cols x 1408 K.
// Threads 0..127 convert the 16x64 f32 A tile (reg-prefetched one step ahead) into
// swizzled LDS + write-through to Abf. All waves gl16-stage the 208x64 B tile.
__global__ __launch_bounds__(256, 5) void k_gemm1(
    const float* __restrict__ images,         // [9216][2048]
    const float* __restrict__ tag,            // [9216][768]
    const unsigned short* __restrict__ Wa,    // [208][2816] bf16
    unsigned short* __restrict__ Abf,         // [9216][3072] (img/tag cols written here)
    float* __restrict__ regP)                 // [2][9216][208] f32 partials
{
    __shared__ __align__(16) unsigned short lds[14336];   // 28,672 B
    unsigned short* ldsA = lds;          // [16][64] swizzled
    unsigned short* ldsB = lds + 1024;   // [208][64] swizzled

    const int t = threadIdx.x;
    const int lane = t & 63;
    const int w = t >> 6;
    const int quad = lane >> 4;
    const int ln15 = lane & 15;
    const int x7 = ln15 & 7;
    const int bid = blockIdx.x;
    const int m0 = (bid >> 1) * 16;
    const int kh = bid & 1;
    const int kbase = kh * 1408;                // 22 K-steps per half
    const int lrow = lane >> 3;
    const int schunk = (lane & 7) ^ lrow;       // inverse-swizzled source 16B chunk
    const int nj = (w == 0) ? 4 : 3;            // j = w + jj*4 covers 0..12

    const bool stA = (t < 128);
    const int sr = t >> 3;                      // 0..15 (when stA)
    const int sgl = t & 7;                      // 0..7
    const int aslot = sr * 64 + ((sgl ^ (sr & 7)) << 3);

    floatx4 acc[4] = {};
    float4 v0, v1;

    if (stA) {    // prologue: prefetch f32 tile 0
        const float* src = (kbase < 2048)
            ? images + (long)(m0 + sr) * 2048 + kbase + sgl * 8
            : tag + (long)(m0 + sr) * 768 + (kbase - 2048) + sgl * 8;
        v0 = *(const float4*)src;
        v1 = *(const float4*)(src + 4);
    }

    for (int kt = 0; kt < 22; ++kt) {
        const int kb = kbase + kt * 64;
        if (stA) {                              // A(kt): regs -> LDS + Abf
            const uint4 pk = pack8(v0, v1);
            *(uint4*)&ldsA[aslot] = pk;
            const int acol = kb + ((kb >= 2048) ? 256 : 0);   // skip boxfeat gap
            *(uint4*)(Abf + (long)(m0 + sr) * K2 + acol + sgl * 8) = pk;
            if (kt < 21) {                      // prefetch f32 tile kt+1
                const int kn = kb + 64;
                const float* src = (kn < 2048)
                    ? images + (long)(m0 + sr) * 2048 + kn + sgl * 8
                    : tag + (long)(m0 + sr) * 768 + (kn - 2048) + sgl * 8;
                v0 = *(const float4*)src;
                v1 = *(const float4*)(src + 4);
            }
        }
#pragma unroll
        for (int i = 0; i < 7; ++i) {           // B(kt): 26 x 1KB units via gl16
            const int u = w + i * 4;
            if (u < 26)
                gl16(Wa + (long)(u * 8 + lrow) * K1 + kb + schunk * 8, ldsB + u * 512);
        }
        __syncthreads();
#pragma unroll
        for (int s = 0; s < 2; ++s) {
            const int g = s * 4 + quad;
            const int co = (g ^ x7) << 3;
            const bf16x8 a = *(const bf16x8*)&ldsA[ln15 * 64 + co];
#pragma unroll
            for (int jj = 0; jj < 4; ++jj) {
                if (jj < nj) {
                    const int j = w + jj * 4;
                    const bf16x8 b = *(const bf16x8*)&ldsB[(j * 16 + ln15) * 64 + co];
                    acc[jj] = __builtin_amdgcn_mfma_f32_16x16x32_bf16(a, b, acc[jj], 0, 0, 0);
                }
            }
        }
        __syncthreads();
    }

    // region partial -> global f32 (C layout: row = quad*4+reg, col = j*16+ln15)
    float* rp = regP + (long)kh * REGN;
#pragma unroll
    for (int jj = 0; jj < 4; ++jj) {
        if (jj < nj) {
            const int j = w + jj * 4;
#pragma unroll
            for (int r = 0; r < 4; ++r)
                rp[(long)(m0 + quad * 4 + r) * 208 + j * 16 + ln15] = acc[jj][r];
        }
    }
}

// ============ attention: one row per wave, grid 2304 x 256 ============
__global__ __launch_bounds__(256, 4) void k_attn(
    const float* __restrict__ regP,     // [2][9216][208]
    const float* __restrict__ boxes,    // [9216][30]
    const float* __restrict__ pos_emb,  // [257][200]
    unsigned short* __restrict__ Abf)   // writes cols 2048..2303
{
    const int t = threadIdx.x;
    const int lane = t & 63;
    const int w = t >> 6;
    const int m = blockIdx.x * 4 + w;

    const float* r0 = regP + (long)m * 208;
    const float* r1 = r0 + REGN;
    float rv[4];
#pragma unroll
    for (int c = 0; c < 4; ++c) {
        const int e = lane + c * 64;
        rv[c] = (e < 200) ? (r0[e] + r1[e]) : 0.0f;
    }
    const float* bx = boxes + (long)m * 30;
    int idx[15]; float bw[15], sc_[15];
#pragma unroll
    for (int k = 0; k < 15; ++k) {
        int ii = (int)bx[k];
        idx[k] = (ii < 0) ? 0 : (ii > 256 ? 256 : ii);
        bw[k] = bx[15 + k];
    }
#pragma unroll
    for (int k = 0; k < 15; ++k) {
        const float* em = pos_emb + (long)idx[k] * 200;
        float p = 0.0f;
#pragma unroll
        for (int c = 0; c < 4; ++c) {
            const int e = lane + c * 64;
            if (e < 200) p += rv[c] * em[e];
        }
        for (int off = 32; off; off >>= 1) p += __shfl_xor(p, off, 64);
        sc_[k] = p;
    }
    float mx = -1e30f;
#pragma unroll
    for (int k = 0; k < 15; ++k) { sc_[k] = tanhf(sc_[k]); mx = fmaxf(mx, sc_[k]); }
    float Z = 0.0f, den = 0.0f, pk[15];
#pragma unroll
    for (int k = 0; k < 15; ++k) { pk[k] = __expf(sc_[k] - mx); Z += pk[k]; }
#pragma unroll
    for (int k = 0; k < 15; ++k) { pk[k] *= bw[k]; den += pk[k]; }
    den += 1e-6f * Z;                 // softmax*w / (sum + eps) exactly
    const float inv = 1.0f / den;
    unsigned short* bo = Abf + (long)m * K2 + 2048;
#pragma unroll
    for (int c = 0; c < 4; ++c) {
        const int e = lane + c * 64;
        float o = 0.0f;
        if (e < 200) {
#pragma unroll
            for (int k = 0; k < 15; ++k) o += pk[k] * pos_emb[(long)idx[k] * 200 + e];
            o *= inv;
        }
        bo[e] = f2bf(o);              // cols 200..255 exact 0 (MUST be finite: x*0=NaN if garbage)
    }
}

// ============ GEMM2: dout(f32) = Abf[9216][3072] @ Wf^T ============
// grid (8,72) n-FASTEST: the 8 blocks sharing an A-panel dispatch back-to-back
// across XCDs -> panel fetched once from HBM/L3. 128x128 tile, 4 blocks/CU.
__global__ __launch_bounds__(256, 4) void k_gemm2(
    const unsigned short* __restrict__ Abf,
    const unsigned short* __restrict__ Wf,
    float* __restrict__ dout)
{
    __shared__ __align__(16) unsigned short ldsA[128 * 64];
    __shared__ __align__(16) unsigned short ldsB[128 * 64];
    const int t = threadIdx.x;
    const int lane = t & 63;
    const int w = t >> 6;
    const int quad = lane >> 4;
    const int ln15 = lane & 15;
    const int x7 = ln15 & 7;
    const int n0 = blockIdx.x * 128;
    const int m0 = blockIdx.y * 128;
    const int lrow = lane >> 3;
    const int schunk = (lane & 7) ^ lrow;
    const int wm = (w & 1) * 64;
    const int wn = (w >> 1) * 64;

    floatx4 acc[4][4] = {};

    for (int kt = 0; kt < 48; ++kt) {
        const int kb = kt * 64;
#pragma unroll
        for (int i = 0; i < 4; ++i) {
            const int u = w * 4 + i;            // 0..15: 8-row groups
            const int r = u * 8 + lrow;         // 0..127
            gl16(Abf + (long)(m0 + r) * K2 + kb + schunk * 8, ldsA + u * 512);
            gl16(Wf  + (long)(n0 + r) * K2 + kb + schunk * 8, ldsB + u * 512);
        }
        __syncthreads();
#pragma unroll
        for (int s = 0; s < 2; ++s) {
            const int g = s * 4 + quad;
            const int co = (g ^ x7) << 3;
            bf16x8 a[4], b[4];
#pragma unroll
            for (int i = 0; i < 4; ++i)
                a[i] = *(const bf16x8*)&ldsA[(wm + i * 16 + ln15) * 64 + co];
#pragma unroll
            for (int j = 0; j < 4; ++j)
                b[j] = *(const bf16x8*)&ldsB[(wn + j * 16 + ln15) * 64 + co];
#pragma unroll
            for (int i = 0; i < 4; ++i)
#pragma unroll
                for (int j = 0; j < 4; ++j)
                    acc[i][j] = __builtin_amdgcn_mfma_f32_16x16x32_bf16(a[i], b[j], acc[i][j], 0, 0, 0);
        }
        __syncthreads();
    }
#pragma unroll
    for (int i = 0; i < 4; ++i)
#pragma unroll
        for (int j = 0; j < 4; ++j) {
            const int row = m0 + wm + i * 16 + quad * 4;
            const int col = n0 + wn + j * 16 + ln15;
#pragma unroll
            for (int r = 0; r < 4; ++r)
                dout[(long)(row + r) * ES + col] = acc[i][j][r];
        }
}

// ============ bias + L2 normalize, IN-PLACE in d_out (f32) ============
__global__ __launch_bounds__(256) void k_norm(
    float* __restrict__ dout,
    const float* __restrict__ bias)
{
    __shared__ float red[4];
    const int m = blockIdx.x;
    const int t = threadIdx.x;
    float* f = dout + (long)m * ES + t * 4;
    float4 v = *(const float4*)f;
    const float4 bs = *(const float4*)(bias + t * 4);
    v.x += bs.x; v.y += bs.y; v.z += bs.z; v.w += bs.w;
    float ss = v.x * v.x + v.y * v.y + v.z * v.z + v.w * v.w;
    for (int off = 32; off; off >>= 1) ss += __shfl_xor(ss, off, 64);
    if ((t & 63) == 0) red[t >> 6] = ss;
    __syncthreads();
    const float total = red[0] + red[1] + red[2] + red[3];
    const float inv = 1.0f / (sqrtf(total) + 1e-8f);
    float4 o;
    o.x = v.x * inv; o.y = v.y * inv; o.z = v.z * inv; o.w = v.w * inv;
    *(float4*)f = o;
}

// ============ launch ============
extern "C" void kernel_launch(void* const* d_in, const int* in_sizes, int n_in,
                              void* d_out, int out_size, void* d_ws, size_t ws_size,
                              hipStream_t stream) {
    const float* images  = (const float*)d_in[0];
    const float* tag     = (const float*)d_in[1];
    const float* boxes   = (const float*)d_in[2];
    const float* pos_emb = (const float*)d_in[3];
    const float* attn_W  = (const float*)d_in[4];
    const float* fc_W    = (const float*)d_in[5];
    const float* fc_b    = (const float*)d_in[6];
    float* out = (float*)d_out;

    unsigned short* Abf = (unsigned short*)d_ws;            // 56,623,104 B
    unsigned short* Wf  = Abf + (size_t)M_TOT * K2;         //  6,291,456 B
    unsigned short* Wa  = Wf  + (size_t)ES * K2;            //  1,171,456 B
    float* regP = (float*)(Wa + (size_t)208 * K1);          // 15,335,424 B
    // total workspace: 79,421,440 B

    k_prep_w<<<1822, 256, 0, stream>>>(attn_W, fc_W, Wa, Wf);
    k_gemm1 <<<1152, 256, 0, stream>>>(images, tag, Wa, Abf, regP);
    k_attn  <<<2304, 256, 0, stream>>>(regP, boxes, pos_emb, Abf);
    k_gemm2 <<<dim3(8, 72), 256, 0, stream>>>(Abf, Wf, out);
    k_norm  <<<M_TOT, 256, 0, stream>>>(out, fc_b);
}

// Round 7
// 307.529 us; speedup vs baseline: 1.0666x; 1.0666x over previous
//
#include <hip/hip_runtime.h>

// Pipeline (5 kernels + 1 memset):
//   k_prep_w : attn_W -> Wa bf16 (rows 200..207 zero), fc_W -> Wf bf16 (remapped, gap zero)
//   memset   : regP = 0
//   k_gemm1  : region = imgtag @ Wa^T. BM=64, K-SPLIT 4 (grid 576), atomicAdd-combine
//              into single regP. A: f32 -> bf16 fused (reg-prefetch, write-through to
//              Abf). B: Wa via gl16. BM=64 -> 4x B-reuse vs BM=16 (staging wall lever).
//   k_attn   : tanh-softmax attention from regP, boxfeat -> Abf cols 2048..2303
//   k_gemm2  : dout = Abf @ Wf^T, 144x128 tile, 384 thr, grid 512 = exactly 2 blocks/CU
//   k_norm   : bias + L2 normalize in place
// Workspace (71,753,728 B  -- MUST stay < ~79 MB, R6's 94.8 MB crashed the container):
//   Abf[9216][3072] bf16 | Wf[1024][3072] bf16 | Wa[208][2816] bf16 | regP[9216][208] f32
//
// LESSONS: (R3) dbuf+1-barrier kills blocks/CU; __syncthreads drains vmcnt(0) anyway.
// (R2) B direct L2->reg puts scattered-load latency on the MFMA chain.
// (R5) both GEMMs sit at a ~35-40 GB/s/CU global->LDS staging wall -> the lever is
// staged-bytes-per-FLOP (bigger tiles), not more TLP.
// (R6) workspace overflow (94.8 MB) is the likely container-killer -> stay <= 79 MB.

#define M_TOT 9216
#define K1    2816
#define K2    3072
#define ES    1024

typedef __attribute__((ext_vector_type(8))) short bf16x8;
typedef __attribute__((ext_vector_type(4))) float floatx4;

static __device__ __forceinline__ unsigned short f2bf(float f) {
    unsigned int u = __float_as_uint(f);
    u += 0x7fffu + ((u >> 16) & 1u);   // RNE
    return (unsigned short)(u >> 16);
}

static __device__ __forceinline__ uint4 pack8(const float4 f0, const float4 f1) {
    uint4 pk;
    pk.x = (unsigned)f2bf(f0.x) | ((unsigned)f2bf(f0.y) << 16);
    pk.y = (unsigned)f2bf(f0.z) | ((unsigned)f2bf(f0.w) << 16);
    pk.z = (unsigned)f2bf(f1.x) | ((unsigned)f2bf(f1.y) << 16);
    pk.w = (unsigned)f2bf(f1.z) | ((unsigned)f2bf(f1.w) << 16);
    return pk;
}

static __device__ __forceinline__ void cvt8(const float* __restrict__ g,
                                            unsigned short* __restrict__ d) {
    *(uint4*)d = pack8(*(const float4*)g, *(const float4*)(g + 4));
}

// async global->LDS, 16 B per lane; LDS dest must be wave-uniform base (+lane*16)
static __device__ __forceinline__ void gl16(const void* g, const void* l) {
    __builtin_amdgcn_global_load_lds(
        (const __attribute__((address_space(1))) unsigned int*)g,
        (__attribute__((address_space(3))) unsigned int*)(unsigned int)(unsigned long long)l,
        16, 0, 0);
}

// ============ prep weights only: Wa + Wf (bf16, padded/remapped) ============
#define NC_WF  (1024 * 384)
#define NC_WA  ( 208 * 352)
__global__ __launch_bounds__(256) void k_prep_w(
    const float* __restrict__ attn_W,   // [200][2816]
    const float* __restrict__ fc_W,     // [1024][3016]
    unsigned short* __restrict__ Wa,    // [208][2816]
    unsigned short* __restrict__ Wf)    // [1024][3072]
{
    const int u = blockIdx.x * 256 + threadIdx.x;
    uint4 z; z.x = z.y = z.z = z.w = 0u;
    if (u < NC_WF) {
        const int r = u / 384;
        const int dc = (u - r * 384) * 8;
        unsigned short* d = Wf + (long)r * K2 + dc;
        if (dc < 2248)      cvt8(fc_W + (long)r * 3016 + dc, d);        // img+box cols
        else if (dc < 2304) *(uint4*)d = z;                             // zero gap
        else                cvt8(fc_W + (long)r * 3016 + (dc - 56), d); // tag cols
    } else if (u < NC_WF + NC_WA) {
        const int v = u - NC_WF;
        const int r = v / 352;
        const int c = (v - r * 352) * 8;
        if (r < 200) cvt8(attn_W + (long)r * K1 + c, Wa + (long)r * K1 + c);
        else         *(uint4*)(Wa + (long)r * K1 + c) = z;
    }
}

// ============ GEMM1: region, BM=64, K-split 4, atomicAdd combine ============
// grid 576 x 256. Block (bid>>2 = m-tile of 64 rows, bid&3 = K-quarter of 704).
// All threads: stage 64x64 f32 A tile (2 chunks each, reg-prefetched) -> swizzled LDS
// + write-through to Abf; gl16-stage the 208x64 B tile; 4 waves x 13 j-tiles MFMA.
__global__ __launch_bounds__(256, 4) void k_gemm1(
    const float* __restrict__ images,         // [9216][2048]
    const float* __restrict__ tag,            // [9216][768]
    const unsigned short* __restrict__ Wa,    // [208][2816] bf16
    unsigned short* __restrict__ Abf,         // [9216][3072] (img/tag cols written here)
    float* __restrict__ regP)                 // [9216][208] f32, pre-zeroed
{
    __shared__ __align__(16) unsigned short ldsA[64 * 64];    //  8,192 B
    __shared__ __align__(16) unsigned short ldsB[208 * 64];   // 26,624 B

    const int t = threadIdx.x;
    const int lane = t & 63;
    const int w = t >> 6;
    const int quad = lane >> 4;
    const int ln15 = lane & 15;
    const int x7 = ln15 & 7;
    const int bid = blockIdx.x;
    const int m0 = (bid >> 2) * 64;
    const int kh = bid & 3;
    const int kbase = kh * 704;                 // 11 K-steps per quarter
    const int lrow = lane >> 3;
    const int schunk = (lane & 7) ^ lrow;       // inverse-swizzled source 16B chunk

    // A staging: thread t handles rows rA, rA+32 at granule gA
    const int rA = t >> 3;                      // 0..31
    const int gA = t & 7;
    const int aslot0 = rA * 64 + ((gA ^ (rA & 7)) << 3);
    const int aslot1 = (rA + 32) * 64 + ((gA ^ (rA & 7)) << 3);   // (rA+32)&7 == rA&7

    floatx4 acc[13] = {};
    float4 p0a, p0b, p1a, p1b;

    // prologue: prefetch f32 A tile for kt=0
    {
        const float* s0 = (kbase < 2048)
            ? images + (long)(m0 + rA) * 2048 + kbase + gA * 8
            : tag + (long)(m0 + rA) * 768 + (kbase - 2048) + gA * 8;
        const float* s1 = (kbase < 2048)
            ? images + (long)(m0 + rA + 32) * 2048 + kbase + gA * 8
            : tag + (long)(m0 + rA + 32) * 768 + (kbase - 2048) + gA * 8;
        p0a = *(const float4*)s0; p0b = *(const float4*)(s0 + 4);
        p1a = *(const float4*)s1; p1b = *(const float4*)(s1 + 4);
    }

    for (int kt = 0; kt < 11; ++kt) {
        const int kb = kbase + kt * 64;
        // A(kt): regs -> swizzled LDS + Abf write-through
        {
            const uint4 k0 = pack8(p0a, p0b);
            const uint4 k1 = pack8(p1a, p1b);
            *(uint4*)&ldsA[aslot0] = k0;
            *(uint4*)&ldsA[aslot1] = k1;
            const int acol = kb + ((kb >= 2048) ? 256 : 0);   // skip boxfeat gap
            *(uint4*)(Abf + (long)(m0 + rA) * K2 + acol + gA * 8) = k0;
            *(uint4*)(Abf + (long)(m0 + rA + 32) * K2 + acol + gA * 8) = k1;
        }
#pragma unroll
        for (int i = 0; i < 7; ++i) {           // B(kt): 26 x 1KB units via gl16
            const int u = w + i * 4;
            if (u < 26)
                gl16(Wa + (long)(u * 8 + lrow) * K1 + kb + schunk * 8, ldsB + u * 512);
        }
        if (kt < 10) {                          // prefetch f32 A tile kt+1
            const int kn = kb + 64;
            const float* s0 = (kn < 2048)
                ? images + (long)(m0 + rA) * 2048 + kn + gA * 8
                : tag + (long)(m0 + rA) * 768 + (kn - 2048) + gA * 8;
            const float* s1 = (kn < 2048)
                ? images + (long)(m0 + rA + 32) * 2048 + kn + gA * 8
                : tag + (long)(m0 + rA + 32) * 768 + (kn - 2048) + gA * 8;
            p0a = *(const float4*)s0; p0b = *(const float4*)(s0 + 4);
            p1a = *(const float4*)s1; p1b = *(const float4*)(s1 + 4);
        }
        __syncthreads();
        // wave w computes rows w*16..w*16+15 x all 13 j-tiles
#pragma unroll
        for (int s = 0; s < 2; ++s) {
            const int g = s * 4 + quad;
            const int co = (g ^ x7) << 3;
            const bf16x8 a = *(const bf16x8*)&ldsA[(w * 16 + ln15) * 64 + co];
#pragma unroll
            for (int j = 0; j < 13; ++j) {
                const bf16x8 b = *(const bf16x8*)&ldsB[(j * 16 + ln15) * 64 + co];
                acc[j] = __builtin_amdgcn_mfma_f32_16x16x32_bf16(a, b, acc[j], 0, 0, 0);
            }
        }
        __syncthreads();
    }

    // partial -> regP via atomicAdd (device-scope; 4 addends per address)
#pragma unroll
    for (int j = 0; j < 13; ++j)
#pragma unroll
        for (int r = 0; r < 4; ++r)
            atomicAdd(&regP[(long)(m0 + w * 16 + quad * 4 + r) * 208 + j * 16 + ln15],
                      acc[j][r]);
}

// ============ attention: one row per wave, grid 2304 x 256 ============
__global__ __launch_bounds__(256, 4) void k_attn(
    const float* __restrict__ regP,     // [9216][208]
    const float* __restrict__ boxes,    // [9216][30]
    const float* __restrict__ pos_emb,  // [257][200]
    unsigned short* __restrict__ Abf)   // writes cols 2048..2303
{
    const int t = threadIdx.x;
    const int lane = t & 63;
    const int w = t >> 6;
    const int m = blockIdx.x * 4 + w;

    const float* r0 = regP + (long)m * 208;
    float rv[4];
#pragma unroll
    for (int c = 0; c < 4; ++c) {
        const int e = lane + c * 64;
        rv[c] = (e < 200) ? r0[e] : 0.0f;
    }
    const float* bx = boxes + (long)m * 30;
    int idx[15]; float bw[15], sc_[15];
#pragma unroll
    for (int k = 0; k < 15; ++k) {
        int ii = (int)bx[k];
        idx[k] = (ii < 0) ? 0 : (ii > 256 ? 256 : ii);
        bw[k] = bx[15 + k];
    }
#pragma unroll
    for (int k = 0; k < 15; ++k) {
        const float* em = pos_emb + (long)idx[k] * 200;
        float p = 0.0f;
#pragma unroll
        for (int c = 0; c < 4; ++c) {
            const int e = lane + c * 64;
            if (e < 200) p += rv[c] * em[e];
        }
        for (int off = 32; off; off >>= 1) p += __shfl_xor(p, off, 64);
        sc_[k] = p;
    }
    float mx = -1e30f;
#pragma unroll
    for (int k = 0; k < 15; ++k) { sc_[k] = tanhf(sc_[k]); mx = fmaxf(mx, sc_[k]); }
    float Z = 0.0f, den = 0.0f, pk[15];
#pragma unroll
    for (int k = 0; k < 15; ++k) { pk[k] = __expf(sc_[k] - mx); Z += pk[k]; }
#pragma unroll
    for (int k = 0; k < 15; ++k) { pk[k] *= bw[k]; den += pk[k]; }
    den += 1e-6f * Z;                 // softmax*w / (sum + eps) exactly
    const float inv = 1.0f / den;
    unsigned short* bo = Abf + (long)m * K2 + 2048;
#pragma unroll
    for (int c = 0; c < 4; ++c) {
        const int e = lane + c * 64;
        float o = 0.0f;
        if (e < 200) {
#pragma unroll
            for (int k = 0; k < 15; ++k) o += pk[k] * pos_emb[(long)idx[k] * 200 + e];
            o *= inv;
        }
        bo[e] = f2bf(o);              // cols 200..255 exact 0 (x*garbage would NaN)
    }
}

// ============ GEMM2: dout(f32) = Abf[9216][3072] @ Wf^T ============
// 144x128 tile, 384 threads (3m x 2n waves), grid 512 = exactly 2 blocks/CU (balanced).
// nx = bid&7 -> one Wf N-panel per XCD L2.
__global__ __launch_bounds__(384, 3) void k_gemm2(
    const unsigned short* __restrict__ Abf,
    const unsigned short* __restrict__ Wf,
    float* __restrict__ dout)
{
    __shared__ __align__(16) unsigned short ldsA[144 * 64];   // 18,432 B
    __shared__ __align__(16) unsigned short ldsB[128 * 64];   // 16,384 B
    const int t = threadIdx.x;
    const int lane = t & 63;
    const int w = t >> 6;                 // 0..5
    const int quad = lane >> 4;
    const int ln15 = lane & 15;
    const int x7 = ln15 & 7;
    const int nx = blockIdx.x & 7;        // 8 XCDs round-robin consecutive bids
    const int mx = blockIdx.x >> 3;       // 0..63
    const int m0 = mx * 144;
    const int n0 = nx * 128;
    const int lrow = lane >> 3;
    const int schunk = (lane & 7) ^ lrow;
    const int wm = (w % 3) * 48;
    const int wn = (w / 3) * 64;

    floatx4 acc[3][4] = {};

    for (int kt = 0; kt < 48; ++kt) {
        const int kb = kt * 64;
#pragma unroll
        for (int i = 0; i < 6; ++i) {
            const int u = w + i * 6;      // 34 units: 0..17 = A (144 rows), 18..33 = B (128)
            if (u < 18)
                gl16(Abf + (long)(m0 + u * 8 + lrow) * K2 + kb + schunk * 8, ldsA + u * 512);
            else if (u < 34)
                gl16(Wf + (long)(n0 + (u - 18) * 8 + lrow) * K2 + kb + schunk * 8,
                     ldsB + (u - 18) * 512);
        }
        __syncthreads();
#pragma unroll
        for (int s = 0; s < 2; ++s) {
            const int g = s * 4 + quad;
            const int co = (g ^ x7) << 3;
            bf16x8 a[3], b[4];
#pragma unroll
            for (int i = 0; i < 3; ++i)
                a[i] = *(const bf16x8*)&ldsA[(wm + i * 16 + ln15) * 64 + co];
#pragma unroll
            for (int j = 0; j < 4; ++j)
                b[j] = *(const bf16x8*)&ldsB[(wn + j * 16 + ln15) * 64 + co];
#pragma unroll
            for (int i = 0; i < 3; ++i)
#pragma unroll
                for (int j = 0; j < 4; ++j)
                    acc[i][j] = __builtin_amdgcn_mfma_f32_16x16x32_bf16(a[i], b[j], acc[i][j], 0, 0, 0);
        }
        __syncthreads();
    }
#pragma unroll
    for (int i = 0; i < 3; ++i)
#pragma unroll
        for (int j = 0; j < 4; ++j) {
            const int row = m0 + wm + i * 16 + quad * 4;
            const int col = n0 + wn + j * 16 + ln15;
#pragma unroll
            for (int r = 0; r < 4; ++r)
                dout[(long)(row + r) * ES + col] = acc[i][j][r];
        }
}

// ============ bias + L2 normalize, IN-PLACE in d_out (f32) ============
__global__ __launch_bounds__(256) void k_norm(
    float* __restrict__ dout,
    const float* __restrict__ bias)
{
    __shared__ float red[4];
    const int m = blockIdx.x;
    const int t = threadIdx.x;
    float* f = dout + (long)m * ES + t * 4;
    float4 v = *(const float4*)f;
    const float4 bs = *(const float4*)(bias + t * 4);
    v.x += bs.x; v.y += bs.y; v.z += bs.z; v.w += bs.w;
    float ss = v.x * v.x + v.y * v.y + v.z * v.z + v.w * v.w;
    for (int off = 32; off; off >>= 1) ss += __shfl_xor(ss, off, 64);
    if ((t & 63) == 0) red[t >> 6] = ss;
    __syncthreads();
    const float total = red[0] + red[1] + red[2] + red[3];
    const float inv = 1.0f / (sqrtf(total) + 1e-8f);
    float4 o;
    o.x = v.x * inv; o.y = v.y * inv; o.z = v.z * inv; o.w = v.w * inv;
    *(float4*)f = o;
}

// ============ launch ============
extern "C" void kernel_launch(void* const* d_in, const int* in_sizes, int n_in,
                              void* d_out, int out_size, void* d_ws, size_t ws_size,
                              hipStream_t stream) {
    const float* images  = (const float*)d_in[0];
    const float* tag     = (const float*)d_in[1];
    const float* boxes   = (const float*)d_in[2];
    const float* pos_emb = (const float*)d_in[3];
    const float* attn_W  = (const float*)d_in[4];
    const float* fc_W    = (const float*)d_in[5];
    const float* fc_b    = (const float*)d_in[6];
    float* out = (float*)d_out;

    unsigned short* Abf = (unsigned short*)d_ws;            // 56,623,104 B
    unsigned short* Wf  = Abf + (size_t)M_TOT * K2;         //  6,291,456 B
    unsigned short* Wa  = Wf  + (size_t)ES * K2;            //  1,171,456 B
    float* regP = (float*)(Wa + (size_t)208 * K1);          //  7,667,712 B
    // total workspace: 71,753,728 B

    k_prep_w<<<1822, 256, 0, stream>>>(attn_W, fc_W, Wa, Wf);
    hipMemsetAsync(regP, 0, (size_t)M_TOT * 208 * sizeof(float), stream);
    k_gemm1 <<<576, 256, 0, stream>>>(images, tag, Wa, Abf, regP);
    k_attn  <<<2304, 256, 0, stream>>>(regP, boxes, pos_emb, Abf);
    k_gemm2 <<<512, 384, 0, stream>>>(Abf, Wf, out);
    k_norm  <<<M_TOT, 256, 0, stream>>>(out, fc_b);
}